// Round 6
// baseline (390.790 us; speedup 1.0000x reference)
//
#include <hip/hip_runtime.h>
#include <hip/hip_bf16.h>
#include <math.h>

#define TT   1024
#define HH   1024
#define II   512
#define EE   32
#define NE   40
#define TOPK 4
#define CAP  1024

#define GM  128   // m-tile (slots) per block pass
#define GK  32    // k-slab per pipeline phase

typedef __attribute__((ext_vector_type(4))) short short4v;
typedef __attribute__((ext_vector_type(8))) short short8v;
typedef __attribute__((ext_vector_type(4))) float floatx4;

static __device__ __forceinline__ short f2bf(float f) {
    unsigned u = __float_as_uint(f);
    unsigned r = (u + 0x7fffu + ((u >> 16) & 1u)) >> 16;
    return (short)(r & 0xffffu);
}
static __device__ __forceinline__ float bf2f(short s) {
    return __uint_as_float(((unsigned)(unsigned short)s) << 16);
}
#if defined(__has_builtin)
#if __has_builtin(__builtin_amdgcn_cvt_pk_bf16_f32)
#define HAVE_PK_BF16 1
#endif
#endif
static __device__ __forceinline__ unsigned pk2(float a, float b) {
#ifdef HAVE_PK_BF16
    typedef __attribute__((ext_vector_type(2))) __bf16 bf2t;
    union { bf2t v; unsigned u; } cv;
    cv.v = __builtin_amdgcn_cvt_pk_bf16_f32(a, b);
    return cv.u;
#else
    return (unsigned)(unsigned short)f2bf(a) | ((unsigned)(unsigned short)f2bf(b) << 16);
#endif
}
static __device__ __forceinline__ short4v cvt4(float4 v) {
    union { unsigned u[2]; short4v s; } cv;
    cv.u[0] = pk2(v.x, v.y); cv.u[1] = pk2(v.z, v.w);
    return cv.s;
}
// pack 8 consecutive fp32 (two float4) into a bf16 MFMA fragment register
static __device__ __forceinline__ short8v pack8(float4 f0, float4 f1) {
    union { short4v h[2]; short8v v; } u;
    u.h[0] = cvt4(f0); u.h[1] = cvt4(f1);
    return u.v;
}

// ---------------- workspace layout (bytes) ----------------
// counts @0, topk_w @1024, zero_w @17408, kexp @21504, slots @40960,
// xb @262144 (2MB), hmid @2359296 (4MB), ydown @6553600 (8MB)

// ================= Phase A: router (waves 0,1) + xconv (waves 2,3) ============
// No atomics / no slot building here — kA2 compacts slot lists afterwards.
__global__ __launch_bounds__(256, 4) void kA(
    const float* __restrict__ x, const float* __restrict__ rw,
    const float* __restrict__ bias, float* __restrict__ topk_w,
    float* __restrict__ zero_w, int* __restrict__ kexp,
    short* __restrict__ xb)
{
    const int bx = blockIdx.x, tid = threadIdx.x;
    const int lane = tid & 63;
    const int w    = tid >> 6;

    if (w < 2) {
        const int t = bx * 2 + w;
        float xv[16];
        #pragma unroll
        for (int i = 0; i < 16; ++i) xv[i] = x[(size_t)t * HH + 64 * i + lane];

        float mylogit = -INFINITY;
        for (int e0 = 0; e0 < NE; e0 += 4) {
            const float* r0 = rw + (size_t)e0 * HH;
            float p[4] = { 0.f, 0.f, 0.f, 0.f };
            #pragma unroll
            for (int i = 0; i < 16; ++i) {
                int h = 64 * i + lane;
                #pragma unroll
                for (int j = 0; j < 4; ++j) p[j] += xv[i] * r0[(size_t)j * HH + h];
            }
            #pragma unroll
            for (int j = 0; j < 4; ++j) {
                #pragma unroll
                for (int off = 32; off > 0; off >>= 1) p[j] += __shfl_xor(p[j], off);
                if (lane == e0 + j) mylogit = p[j];
            }
        }

        float m = mylogit;
        #pragma unroll
        for (int off = 32; off > 0; off >>= 1) m = fmaxf(m, __shfl_xor(m, off));
        float pexp = (lane < NE) ? expf(mylogit - m) : 0.f;
        float s = pexp;
        #pragma unroll
        for (int off = 32; off > 0; off >>= 1) s += __shfl_xor(s, off);
        const float score = pexp / s;

        float val = (lane < NE) ? score + bias[lane] : -INFINITY;
        int   kidx[TOPK];
        float kw[TOPK];
        #pragma unroll
        for (int k = 0; k < TOPK; ++k) {
            float v = val; int idx = lane;
            #pragma unroll
            for (int off = 32; off > 0; off >>= 1) {
                float ov = __shfl_xor(v, off);
                int   oi = __shfl_xor(idx, off);
                if (ov > v || (ov == v && oi < idx)) { v = ov; idx = oi; }
            }
            kidx[k] = idx;
            kw[k]   = __shfl(score, idx);
            if (lane == idx) val = -INFINITY;
        }

        if (lane == 0) {
            float zw = 0.f;
            #pragma unroll
            for (int k = 0; k < TOPK; ++k) {
                int slot = t * TOPK + k;
                topk_w[slot] = kw[k];
                kexp[slot]   = kidx[k];
                if (kidx[k] >= EE) zw += kw[k];
            }
            zero_w[t] = zw;
        }
    } else {
        const int t = bx * 2 + (w - 2);
        const float4* xr = (const float4*)(x + (size_t)t * HH);
        short4v* xbr = (short4v*)(xb + (size_t)t * HH);
        #pragma unroll
        for (int i = 0; i < 4; ++i) xbr[lane + 64 * i] = cvt4(xr[lane + 64 * i]);
    }
}

// ================= Phase A2: per-expert slot compaction (token-ordered) =======
// 32 blocks, one expert each. Ballot + block scan; no atomics, no memset needed.
__global__ __launch_bounds__(256, 4) void kA2(
    const int* __restrict__ kexp, int* __restrict__ counts,
    int* __restrict__ slots)
{
    __shared__ int wsum[4];
    __shared__ int base;
    const int e = blockIdx.x;
    const int tid = threadIdx.x, lane = tid & 63, w = tid >> 6;
    if (tid == 0) base = 0;
    __syncthreads();
    for (int i0 = 0; i0 < TT * TOPK; i0 += 256) {
        const int i = i0 + tid;
        const bool m = (kexp[i] == e);
        unsigned long long bal = __ballot(m);
        int pre  = __popcll(bal & ((1ull << lane) - 1ull));
        int wcnt = __popcll(bal);
        if (lane == 0) wsum[w] = wcnt;
        __syncthreads();
        int woff = 0;
        #pragma unroll
        for (int j = 0; j < 4; ++j) if (j < w) woff += wsum[j];
        const int tot = wsum[0] + wsum[1] + wsum[2] + wsum[3];
        if (m) slots[e * CAP + base + woff + pre] = i;
        __syncthreads();
        if (tid == 0) base += tot;
        __syncthreads();
    }
    if (tid == 0) counts[e] = base;
}

// ================= Phase B: gate_up bf16 MFMA + SiLU ==========================
// grid 1024 = E(32) x 32 tiles of 16 hmid cols. 4 waves split M (32 rows each).
// Direct-from-global fragments; B (weights) 4-deep prefetch, A (xb) 2-deep.
__global__ __launch_bounds__(256, 3) void kB(
    const short* __restrict__ xb, const float* __restrict__ wgu,
    const int* __restrict__ counts, const int* __restrict__ slots,
    const float* __restrict__ topk_w, short* __restrict__ hmid)
{
    __shared__ int   ssl[GM];
    __shared__ float swv[GM];
    const int bx = blockIdx.x, tid = threadIdx.x;
    const int e      = bx >> 5;
    const int c_base = (bx & 31) * 16;
    const int cnt    = counts[e];
    const float* wb  = wgu + (size_t)e * (2 * II) * HH;

    const int lane = tid & 63;
    const int w    = tid >> 6;        // wave owns m-rows [w*32, w*32+32)
    const int quad = lane >> 4;
    const int mcol = lane & 15;
    constexpr int NSLAB = HH / GK;    // 32 (multiple of 4)

    const float* pG = wb + (size_t)(c_base + mcol) * HH + quad * 8;
    const float* pU = wb + (size_t)(II + c_base + mcol) * HH + quad * 8;

    for (int m_base = 0; m_base < cnt; m_base += GM) {
        __syncthreads();
        if (tid < GM) {
            int m = m_base + tid;
            int s = (m < cnt) ? slots[e * CAP + m] : -1;
            ssl[tid] = s;
            swv[tid] = (s >= 0) ? topk_w[s] : 0.f;
        }
        __syncthreads();

        const short *pA0, *pA1;
        {
            int s0 = ssl[w * 32 +      mcol];
            int s1 = ssl[w * 32 + 16 + mcol];
            pA0 = xb + (size_t)((s0 >= 0 ? s0 : 0) >> 2) * HH + quad * 8;
            pA1 = xb + (size_t)((s1 >= 0 ? s1 : 0) >> 2) * HH + quad * 8;
        }

        floatx4 accg0 = {}, accg1 = {}, accu0 = {}, accu1 = {};

        float4 g0_0,g1_0,u0_0,u1_0, g0_1,g1_1,u0_1,u1_1,
               g0_2,g1_2,u0_2,u1_2, g0_3,g1_3,u0_3,u1_3;
        short8v a0_0,a1_0, a0_1,a1_1;

        // prologue: B slabs 0..3, A slabs 0..1
        g0_0=*(const float4*)(pG       ); g1_0=*(const float4*)(pG+4       );
        u0_0=*(const float4*)(pU       ); u1_0=*(const float4*)(pU+4       );
        g0_1=*(const float4*)(pG+GK    ); g1_1=*(const float4*)(pG+GK+4    );
        u0_1=*(const float4*)(pU+GK    ); u1_1=*(const float4*)(pU+GK+4    );
        g0_2=*(const float4*)(pG+2*GK  ); g1_2=*(const float4*)(pG+2*GK+4  );
        u0_2=*(const float4*)(pU+2*GK  ); u1_2=*(const float4*)(pU+2*GK+4  );
        g0_3=*(const float4*)(pG+3*GK  ); g1_3=*(const float4*)(pG+3*GK+4  );
        u0_3=*(const float4*)(pU+3*GK  ); u1_3=*(const float4*)(pU+3*GK+4  );
        a0_0=*(const short8v*)(pA0     ); a1_0=*(const short8v*)(pA1     );
        a0_1=*(const short8v*)(pA0+GK  ); a1_1=*(const short8v*)(pA1+GK  );

        for (int t = 0; t < NSLAB; t += 4) {
            // phase 0: slab t (B set0, A set0); refill B<-t+4, A<-t+2
            {
                short8v bg = pack8(g0_0,g1_0), bu = pack8(u0_0,u1_0);
                accg0 = __builtin_amdgcn_mfma_f32_16x16x32_bf16(a0_0, bg, accg0, 0, 0, 0);
                accu0 = __builtin_amdgcn_mfma_f32_16x16x32_bf16(a0_0, bu, accu0, 0, 0, 0);
                accg1 = __builtin_amdgcn_mfma_f32_16x16x32_bf16(a1_0, bg, accg1, 0, 0, 0);
                accu1 = __builtin_amdgcn_mfma_f32_16x16x32_bf16(a1_0, bu, accu1, 0, 0, 0);
                const int kb_ = (t + 4) * GK;
                if (kb_ < HH) {
                    g0_0=*(const float4*)(pG+kb_); g1_0=*(const float4*)(pG+kb_+4);
                    u0_0=*(const float4*)(pU+kb_); u1_0=*(const float4*)(pU+kb_+4);
                }
                const int ka_ = (t + 2) * GK;
                if (ka_ < HH) { a0_0=*(const short8v*)(pA0+ka_); a1_0=*(const short8v*)(pA1+ka_); }
            }
            // phase 1: slab t+1 (B set1, A set1); refill B<-t+5, A<-t+3
            {
                short8v bg = pack8(g0_1,g1_1), bu = pack8(u0_1,u1_1);
                accg0 = __builtin_amdgcn_mfma_f32_16x16x32_bf16(a0_1, bg, accg0, 0, 0, 0);
                accu0 = __builtin_amdgcn_mfma_f32_16x16x32_bf16(a0_1, bu, accu0, 0, 0, 0);
                accg1 = __builtin_amdgcn_mfma_f32_16x16x32_bf16(a1_1, bg, accg1, 0, 0, 0);
                accu1 = __builtin_amdgcn_mfma_f32_16x16x32_bf16(a1_1, bu, accu1, 0, 0, 0);
                const int kb_ = (t + 5) * GK;
                if (kb_ < HH) {
                    g0_1=*(const float4*)(pG+kb_); g1_1=*(const float4*)(pG+kb_+4);
                    u0_1=*(const float4*)(pU+kb_); u1_1=*(const float4*)(pU+kb_+4);
                }
                const int ka_ = (t + 3) * GK;
                if (ka_ < HH) { a0_1=*(const short8v*)(pA0+ka_); a1_1=*(const short8v*)(pA1+ka_); }
            }
            // phase 2: slab t+2 (B set2, A set0); refill B<-t+6, A<-t+4
            {
                short8v bg = pack8(g0_2,g1_2), bu = pack8(u0_2,u1_2);
                accg0 = __builtin_amdgcn_mfma_f32_16x16x32_bf16(a0_0, bg, accg0, 0, 0, 0);
                accu0 = __builtin_amdgcn_mfma_f32_16x16x32_bf16(a0_0, bu, accu0, 0, 0, 0);
                accg1 = __builtin_amdgcn_mfma_f32_16x16x32_bf16(a1_0, bg, accg1, 0, 0, 0);
                accu1 = __builtin_amdgcn_mfma_f32_16x16x32_bf16(a1_0, bu, accu1, 0, 0, 0);
                const int kb_ = (t + 6) * GK;
                if (kb_ < HH) {
                    g0_2=*(const float4*)(pG+kb_); g1_2=*(const float4*)(pG+kb_+4);
                    u0_2=*(const float4*)(pU+kb_); u1_2=*(const float4*)(pU+kb_+4);
                }
                const int ka_ = (t + 4) * GK;
                if (ka_ < HH) { a0_0=*(const short8v*)(pA0+ka_); a1_0=*(const short8v*)(pA1+ka_); }
            }
            // phase 3: slab t+3 (B set3, A set1); refill B<-t+7, A<-t+5
            {
                short8v bg = pack8(g0_3,g1_3), bu = pack8(u0_3,u1_3);
                accg0 = __builtin_amdgcn_mfma_f32_16x16x32_bf16(a0_1, bg, accg0, 0, 0, 0);
                accu0 = __builtin_amdgcn_mfma_f32_16x16x32_bf16(a0_1, bu, accu0, 0, 0, 0);
                accg1 = __builtin_amdgcn_mfma_f32_16x16x32_bf16(a1_1, bg, accg1, 0, 0, 0);
                accu1 = __builtin_amdgcn_mfma_f32_16x16x32_bf16(a1_1, bu, accu1, 0, 0, 0);
                const int kb_ = (t + 7) * GK;
                if (kb_ < HH) {
                    g0_3=*(const float4*)(pG+kb_); g1_3=*(const float4*)(pG+kb_+4);
                    u0_3=*(const float4*)(pU+kb_); u1_3=*(const float4*)(pU+kb_+4);
                }
                const int ka_ = (t + 5) * GK;
                if (ka_ < HH) { a0_1=*(const short8v*)(pA0+ka_); a1_1=*(const short8v*)(pA1+ka_); }
            }
        }

        #pragma unroll
        for (int r = 0; r < 4; ++r) {
            int m0 = w * 32 + quad * 4 + r;
            int s0 = ssl[m0];
            if (s0 >= 0) {
                float g = accg0[r], u = accu0[r];
                hmid[(size_t)s0 * II + c_base + mcol] =
                    f2bf(swv[m0] * g * u / (1.f + __expf(-g)));
            }
            int m1 = w * 32 + 16 + quad * 4 + r;
            int s1 = ssl[m1];
            if (s1 >= 0) {
                float g = accg1[r], u = accu1[r];
                hmid[(size_t)s1 * II + c_base + mcol] =
                    f2bf(swv[m1] * g * u / (1.f + __expf(-g)));
            }
        }
    }
}

// ================= Phase C: down bf16 MFMA -> ydown ===========================
// grid 1024 = E(32) x 32 tiles of 32 out cols. 4 waves split M (32 rows each).
// B (wd) 4-deep, A (hmid) 2-deep. NSLAB = 16.
__global__ __launch_bounds__(256, 3) void kC(
    const short* __restrict__ hmid, const float* __restrict__ wd,
    const int* __restrict__ counts, const int* __restrict__ slots,
    short* __restrict__ ydown)
{
    __shared__ int ssl[GM];
    const int bx = blockIdx.x, tid = threadIdx.x;
    const int e      = bx >> 5;
    const int n_base = (bx & 31) * 32;
    const int cnt    = counts[e];
    const float* wb  = wd + (size_t)e * HH * II;

    const int lane = tid & 63;
    const int w    = tid >> 6;
    const int quad = lane >> 4;
    const int mcol = lane & 15;
    constexpr int NSLAB = II / GK;    // 16 (multiple of 4)

    const float* pW0 = wb + (size_t)(n_base +      mcol) * II + quad * 8;
    const float* pW1 = wb + (size_t)(n_base + 16 + mcol) * II + quad * 8;

    for (int m_base = 0; m_base < cnt; m_base += GM) {
        __syncthreads();
        if (tid < GM) {
            int m = m_base + tid;
            ssl[tid] = (m < cnt) ? slots[e * CAP + m] : -1;
        }
        __syncthreads();

        const short *pA0, *pA1;
        {
            int s0 = ssl[w * 32 +      mcol];
            int s1 = ssl[w * 32 + 16 + mcol];
            pA0 = hmid + (size_t)(s0 >= 0 ? s0 : 0) * II + quad * 8;
            pA1 = hmid + (size_t)(s1 >= 0 ? s1 : 0) * II + quad * 8;
        }

        floatx4 acc00 = {}, acc01 = {}, acc10 = {}, acc11 = {};

        float4 p0_0,p1_0,q0_0,q1_0, p0_1,p1_1,q0_1,q1_1,
               p0_2,p1_2,q0_2,q1_2, p0_3,p1_3,q0_3,q1_3;
        short8v a0_0,a1_0, a0_1,a1_1;

        p0_0=*(const float4*)(pW0      ); p1_0=*(const float4*)(pW0+4      );
        q0_0=*(const float4*)(pW1      ); q1_0=*(const float4*)(pW1+4      );
        p0_1=*(const float4*)(pW0+GK   ); p1_1=*(const float4*)(pW0+GK+4   );
        q0_1=*(const float4*)(pW1+GK   ); q1_1=*(const float4*)(pW1+GK+4   );
        p0_2=*(const float4*)(pW0+2*GK ); p1_2=*(const float4*)(pW0+2*GK+4 );
        q0_2=*(const float4*)(pW1+2*GK ); q1_2=*(const float4*)(pW1+2*GK+4 );
        p0_3=*(const float4*)(pW0+3*GK ); p1_3=*(const float4*)(pW0+3*GK+4 );
        q0_3=*(const float4*)(pW1+3*GK ); q1_3=*(const float4*)(pW1+3*GK+4 );
        a0_0=*(const short8v*)(pA0     ); a1_0=*(const short8v*)(pA1     );
        a0_1=*(const short8v*)(pA0+GK  ); a1_1=*(const short8v*)(pA1+GK  );

        for (int t = 0; t < NSLAB; t += 4) {
            // phase 0
            {
                short8v b0 = pack8(p0_0,p1_0), b1 = pack8(q0_0,q1_0);
                acc00 = __builtin_amdgcn_mfma_f32_16x16x32_bf16(a0_0, b0, acc00, 0, 0, 0);
                acc01 = __builtin_amdgcn_mfma_f32_16x16x32_bf16(a0_0, b1, acc01, 0, 0, 0);
                acc10 = __builtin_amdgcn_mfma_f32_16x16x32_bf16(a1_0, b0, acc10, 0, 0, 0);
                acc11 = __builtin_amdgcn_mfma_f32_16x16x32_bf16(a1_0, b1, acc11, 0, 0, 0);
                const int kb_ = (t + 4) * GK;
                if (kb_ < II) {
                    p0_0=*(const float4*)(pW0+kb_); p1_0=*(const float4*)(pW0+kb_+4);
                    q0_0=*(const float4*)(pW1+kb_); q1_0=*(const float4*)(pW1+kb_+4);
                }
                const int ka_ = (t + 2) * GK;
                if (ka_ < II) { a0_0=*(const short8v*)(pA0+ka_); a1_0=*(const short8v*)(pA1+ka_); }
            }
            // phase 1
            {
                short8v b0 = pack8(p0_1,p1_1), b1 = pack8(q0_1,q1_1);
                acc00 = __builtin_amdgcn_mfma_f32_16x16x32_bf16(a0_1, b0, acc00, 0, 0, 0);
                acc01 = __builtin_amdgcn_mfma_f32_16x16x32_bf16(a0_1, b1, acc01, 0, 0, 0);
                acc10 = __builtin_amdgcn_mfma_f32_16x16x32_bf16(a1_1, b0, acc10, 0, 0, 0);
                acc11 = __builtin_amdgcn_mfma_f32_16x16x32_bf16(a1_1, b1, acc11, 0, 0, 0);
                const int kb_ = (t + 5) * GK;
                if (kb_ < II) {
                    p0_1=*(const float4*)(pW0+kb_); p1_1=*(const float4*)(pW0+kb_+4);
                    q0_1=*(const float4*)(pW1+kb_); q1_1=*(const float4*)(pW1+kb_+4);
                }
                const int ka_ = (t + 3) * GK;
                if (ka_ < II) { a0_1=*(const short8v*)(pA0+ka_); a1_1=*(const short8v*)(pA1+ka_); }
            }
            // phase 2
            {
                short8v b0 = pack8(p0_2,p1_2), b1 = pack8(q0_2,q1_2);
                acc00 = __builtin_amdgcn_mfma_f32_16x16x32_bf16(a0_0, b0, acc00, 0, 0, 0);
                acc01 = __builtin_amdgcn_mfma_f32_16x16x32_bf16(a0_0, b1, acc01, 0, 0, 0);
                acc10 = __builtin_amdgcn_mfma_f32_16x16x32_bf16(a1_0, b0, acc10, 0, 0, 0);
                acc11 = __builtin_amdgcn_mfma_f32_16x16x32_bf16(a1_0, b1, acc11, 0, 0, 0);
                const int kb_ = (t + 6) * GK;
                if (kb_ < II) {
                    p0_2=*(const float4*)(pW0+kb_); p1_2=*(const float4*)(pW0+kb_+4);
                    q0_2=*(const float4*)(pW1+kb_); q1_2=*(const float4*)(pW1+kb_+4);
                }
                const int ka_ = (t + 4) * GK;
                if (ka_ < II) { a0_0=*(const short8v*)(pA0+ka_); a1_0=*(const short8v*)(pA1+ka_); }
            }
            // phase 3
            {
                short8v b0 = pack8(p0_3,p1_3), b1 = pack8(q0_3,q1_3);
                acc00 = __builtin_amdgcn_mfma_f32_16x16x32_bf16(a0_1, b0, acc00, 0, 0, 0);
                acc01 = __builtin_amdgcn_mfma_f32_16x16x32_bf16(a0_1, b1, acc01, 0, 0, 0);
                acc10 = __builtin_amdgcn_mfma_f32_16x16x32_bf16(a1_1, b0, acc10, 0, 0, 0);
                acc11 = __builtin_amdgcn_mfma_f32_16x16x32_bf16(a1_1, b1, acc11, 0, 0, 0);
                const int kb_ = (t + 7) * GK;
                if (kb_ < II) {
                    p0_3=*(const float4*)(pW0+kb_); p1_3=*(const float4*)(pW0+kb_+4);
                    q0_3=*(const float4*)(pW1+kb_); q1_3=*(const float4*)(pW1+kb_+4);
                }
                const int ka_ = (t + 5) * GK;
                if (ka_ < II) { a0_1=*(const short8v*)(pA0+ka_); a1_1=*(const short8v*)(pA1+ka_); }
            }
        }

        #pragma unroll
        for (int r = 0; r < 4; ++r) {
            int m0 = w * 32 + quad * 4 + r;
            int s0 = ssl[m0];
            if (s0 >= 0) {
                short* yrow = ydown + (size_t)s0 * HH + n_base;
                yrow[mcol]      = f2bf(acc00[r]);
                yrow[16 + mcol] = f2bf(acc01[r]);
            }
            int m1 = w * 32 + 16 + quad * 4 + r;
            int s1 = ssl[m1];
            if (s1 >= 0) {
                short* yrow = ydown + (size_t)s1 * HH + n_base;
                yrow[mcol]      = f2bf(acc10[r]);
                yrow[16 + mcol] = f2bf(acc11[r]);
            }
        }
    }
}

// ================= Phase D: combine (grid 1024, 1 token/block) ================
__global__ __launch_bounds__(256, 4) void kD(
    const float* __restrict__ x, const short* __restrict__ ydown,
    const int* __restrict__ kexp, const float* __restrict__ zero_w,
    float* __restrict__ out)
{
    const int bx = blockIdx.x, tid = threadIdx.x;
    const int t = bx;
    const float4 xvv = ((const float4*)(x + (size_t)t * HH))[tid];
    const float zw = zero_w[t];
    float4 o;
    o.x = zw * xvv.x; o.y = zw * xvv.y; o.z = zw * xvv.z; o.w = zw * xvv.w;
    #pragma unroll
    for (int k = 0; k < TOPK; ++k) {
        int slot = t * TOPK + k;
        if (kexp[slot] < EE) {
            short4v y = *(const short4v*)&ydown[(size_t)slot * HH + tid * 4];
            o.x += bf2f(y[0]); o.y += bf2f(y[1]);
            o.z += bf2f(y[2]); o.w += bf2f(y[3]);
        }
    }
    ((float4*)(out + (size_t)t * HH))[tid] = o;
}

extern "C" void kernel_launch(void* const* d_in, const int* in_sizes, int n_in,
                              void* d_out, int out_size, void* d_ws, size_t ws_size,
                              hipStream_t stream) {
    const float* x    = (const float*)d_in[0];
    const float* rw   = (const float*)d_in[1];
    const float* bias = (const float*)d_in[2];
    const float* wgu  = (const float*)d_in[3];
    const float* wd   = (const float*)d_in[4];
    float* out = (float*)d_out;

    char* ws = (char*)d_ws;
    int*   counts = (int*)ws;
    float* topk_w = (float*)(ws + 1024);
    float* zero_w = (float*)(ws + 17408);
    int*   kexp   = (int*)(ws + 21504);
    int*   slots  = (int*)(ws + 40960);
    short* xb     = (short*)(ws + 262144);
    short* hmid   = (short*)(ws + 2359296);
    short* ydown  = (short*)(ws + 6553600);

    kA <<<dim3(512),  dim3(256), 0, stream>>>(x, rw, bias, topk_w, zero_w, kexp, xb);
    kA2<<<dim3(32),   dim3(256), 0, stream>>>(kexp, counts, slots);
    kB <<<dim3(1024), dim3(256), 0, stream>>>(xb, wgu, counts, slots, topk_w, hmid);
    kC <<<dim3(1024), dim3(256), 0, stream>>>(hmid, wd, counts, slots, ydown);
    kD <<<dim3(1024), dim3(256), 0, stream>>>(x, ydown, kexp, zero_w, out);
}

// Round 7
// 351.229 us; speedup vs baseline: 1.1126x; 1.1126x over previous
//
#include <hip/hip_runtime.h>
#include <hip/hip_bf16.h>
#include <math.h>

#define TT   1024
#define HH   1024
#define II   512
#define EE   32
#define NE   40
#define TOPK 4
#define CAP  1024

#define GM  128   // m-tile (slots) per block pass
#define GK  32    // k-slab per pipeline step

typedef __attribute__((ext_vector_type(4))) short short4v;
typedef __attribute__((ext_vector_type(8))) short short8v;
typedef __attribute__((ext_vector_type(4))) float floatx4;

static __device__ __forceinline__ short f2bf(float f) {
    unsigned u = __float_as_uint(f);
    unsigned r = (u + 0x7fffu + ((u >> 16) & 1u)) >> 16;
    return (short)(r & 0xffffu);
}
static __device__ __forceinline__ float bf2f(short s) {
    return __uint_as_float(((unsigned)(unsigned short)s) << 16);
}
#if defined(__has_builtin)
#if __has_builtin(__builtin_amdgcn_cvt_pk_bf16_f32)
#define HAVE_PK_BF16 1
#endif
#endif
static __device__ __forceinline__ unsigned pk2(float a, float b) {
#ifdef HAVE_PK_BF16
    typedef __attribute__((ext_vector_type(2))) __bf16 bf2t;
    union { bf2t v; unsigned u; } cv;
    cv.v = __builtin_amdgcn_cvt_pk_bf16_f32(a, b);
    return cv.u;
#else
    return (unsigned)(unsigned short)f2bf(a) | ((unsigned)(unsigned short)f2bf(b) << 16);
#endif
}
static __device__ __forceinline__ short4v cvt4(float4 v) {
    union { unsigned u[2]; short4v s; } cv;
    cv.u[0] = pk2(v.x, v.y); cv.u[1] = pk2(v.z, v.w);
    return cv.s;
}
// pack 8 consecutive fp32 (two float4) into a bf16 MFMA fragment register
static __device__ __forceinline__ short8v pack8(float4 f0, float4 f1) {
    union { short4v h[2]; short8v v; } u;
    u.h[0] = cvt4(f0); u.h[1] = cvt4(f1);
    return u.v;
}

// ---------------- workspace layout (bytes) ----------------
// counts @0, topk_w @1024, zero_w @17408, kexp @21504, slots @40960,
// xb @262144 (2MB), hmid @2359296 (4MB), ydown @6553600 (8MB)

// ================= Phase A: router (waves 0,1) + xconv (waves 2,3) ============
__global__ __launch_bounds__(256, 4) void kA(
    const float* __restrict__ x, const float* __restrict__ rw,
    const float* __restrict__ bias, float* __restrict__ topk_w,
    float* __restrict__ zero_w, int* __restrict__ kexp,
    short* __restrict__ xb)
{
    const int bx = blockIdx.x, tid = threadIdx.x;
    const int lane = tid & 63;
    const int w    = tid >> 6;

    if (w < 2) {
        const int t = bx * 2 + w;
        float xv[16];
        #pragma unroll
        for (int i = 0; i < 16; ++i) xv[i] = x[(size_t)t * HH + 64 * i + lane];

        float mylogit = -INFINITY;
        for (int e0 = 0; e0 < NE; e0 += 4) {
            const float* r0 = rw + (size_t)e0 * HH;
            float p[4] = { 0.f, 0.f, 0.f, 0.f };
            #pragma unroll
            for (int i = 0; i < 16; ++i) {
                int h = 64 * i + lane;
                #pragma unroll
                for (int j = 0; j < 4; ++j) p[j] += xv[i] * r0[(size_t)j * HH + h];
            }
            #pragma unroll
            for (int j = 0; j < 4; ++j) {
                #pragma unroll
                for (int off = 32; off > 0; off >>= 1) p[j] += __shfl_xor(p[j], off);
                if (lane == e0 + j) mylogit = p[j];
            }
        }

        float m = mylogit;
        #pragma unroll
        for (int off = 32; off > 0; off >>= 1) m = fmaxf(m, __shfl_xor(m, off));
        float pexp = (lane < NE) ? expf(mylogit - m) : 0.f;
        float s = pexp;
        #pragma unroll
        for (int off = 32; off > 0; off >>= 1) s += __shfl_xor(s, off);
        const float score = pexp / s;

        float val = (lane < NE) ? score + bias[lane] : -INFINITY;
        int   kidx[TOPK];
        float kw[TOPK];
        #pragma unroll
        for (int k = 0; k < TOPK; ++k) {
            float v = val; int idx = lane;
            #pragma unroll
            for (int off = 32; off > 0; off >>= 1) {
                float ov = __shfl_xor(v, off);
                int   oi = __shfl_xor(idx, off);
                if (ov > v || (ov == v && oi < idx)) { v = ov; idx = oi; }
            }
            kidx[k] = idx;
            kw[k]   = __shfl(score, idx);
            if (lane == idx) val = -INFINITY;
        }

        if (lane == 0) {
            float zw = 0.f;
            #pragma unroll
            for (int k = 0; k < TOPK; ++k) {
                int slot = t * TOPK + k;
                topk_w[slot] = kw[k];
                kexp[slot]   = kidx[k];
                if (kidx[k] >= EE) zw += kw[k];
            }
            zero_w[t] = zw;
        }
    } else {
        const int t = bx * 2 + (w - 2);
        const float4* xr = (const float4*)(x + (size_t)t * HH);
        short4v* xbr = (short4v*)(xb + (size_t)t * HH);
        #pragma unroll
        for (int i = 0; i < 4; ++i) xbr[lane + 64 * i] = cvt4(xr[lane + 64 * i]);
    }
}

// ================= Phase A2: per-expert slot compaction (token-ordered) =======
__global__ __launch_bounds__(256, 4) void kA2(
    const int* __restrict__ kexp, int* __restrict__ counts,
    int* __restrict__ slots)
{
    __shared__ int wsum[4];
    __shared__ int base;
    const int e = blockIdx.x;
    const int tid = threadIdx.x, lane = tid & 63, w = tid >> 6;
    if (tid == 0) base = 0;
    __syncthreads();
    for (int i0 = 0; i0 < TT * TOPK; i0 += 256) {
        const int i = i0 + tid;
        const bool m = (kexp[i] == e);
        unsigned long long bal = __ballot(m);
        int pre  = __popcll(bal & ((1ull << lane) - 1ull));
        int wcnt = __popcll(bal);
        if (lane == 0) wsum[w] = wcnt;
        __syncthreads();
        int woff = 0;
        #pragma unroll
        for (int j = 0; j < 4; ++j) if (j < w) woff += wsum[j];
        const int tot = wsum[0] + wsum[1] + wsum[2] + wsum[3];
        if (m) slots[e * CAP + base + woff + pre] = i;
        __syncthreads();
        if (tid == 0) base += tot;
        __syncthreads();
    }
    if (tid == 0) counts[e] = base;
}

// ================= Phase B: gate_up bf16 MFMA + SiLU ==========================
// grid 1024 = E(32) x 32 tiles of 16 hmid cols. 4 waves split M (32 rows each).
// Direct-from-global fragments, 2-deep prefetch (round-4 proven, no spill).
__global__ __launch_bounds__(256, 4) void kB(
    const short* __restrict__ xb, const float* __restrict__ wgu,
    const int* __restrict__ counts, const int* __restrict__ slots,
    const float* __restrict__ topk_w, short* __restrict__ hmid)
{
    __shared__ int   ssl[GM];
    __shared__ float swv[GM];
    const int bx = blockIdx.x, tid = threadIdx.x;
    const int e      = bx >> 5;
    const int c_base = (bx & 31) * 16;
    const int cnt    = counts[e];
    const float* wb  = wgu + (size_t)e * (2 * II) * HH;

    const int lane = tid & 63;
    const int w    = tid >> 6;        // wave owns m-rows [w*32, w*32+32)
    const int quad = lane >> 4;
    const int mcol = lane & 15;
    constexpr int NT = HH / GK;       // 32 (even)

    // lane holds W[n = c_base+mcol][k = quad*8 .. +7] (8 contiguous fp32)
    const float* pG = wb + (size_t)(c_base + mcol) * HH + quad * 8;
    const float* pU = wb + (size_t)(II + c_base + mcol) * HH + quad * 8;

    for (int m_base = 0; m_base < cnt; m_base += GM) {
        __syncthreads();
        if (tid < GM) {
            int m = m_base + tid;
            int s = (m < cnt) ? slots[e * CAP + m] : -1;
            ssl[tid] = s;
            swv[tid] = (s >= 0) ? topk_w[s] : 0.f;
        }
        __syncthreads();

        const short *pA0, *pA1;
        {
            int s0 = ssl[w * 32 +      mcol];
            int s1 = ssl[w * 32 + 16 + mcol];
            pA0 = xb + (size_t)((s0 >= 0 ? s0 : 0) >> 2) * HH + quad * 8;
            pA1 = xb + (size_t)((s1 >= 0 ? s1 : 0) >> 2) * HH + quad * 8;
        }

        floatx4 accg0 = {}, accg1 = {}, accu0 = {}, accu1 = {};
        short8v aA0, aA1, aB0, aB1;
        float4  gA0, gA1, uA0, uA1, gB0, gB1, uB0, uB1;

        // prologue: slab 0 -> set A
        aA0 = *(const short8v*)(pA0);
        aA1 = *(const short8v*)(pA1);
        gA0 = *(const float4*)(pG);     gA1 = *(const float4*)(pG + 4);
        uA0 = *(const float4*)(pU);     uA1 = *(const float4*)(pU + 4);

        for (int t = 0; t < NT; t += 2) {
            const int k1 = (t + 1) * GK;
            // issue slab k1 -> set B
            aB0 = *(const short8v*)(pA0 + k1);
            aB1 = *(const short8v*)(pA1 + k1);
            gB0 = *(const float4*)(pG + k1); gB1 = *(const float4*)(pG + k1 + 4);
            uB0 = *(const float4*)(pU + k1); uB1 = *(const float4*)(pU + k1 + 4);
            // compute set A (slab t)
            {
                short8v bg = pack8(gA0, gA1), bu = pack8(uA0, uA1);
                accg0 = __builtin_amdgcn_mfma_f32_16x16x32_bf16(aA0, bg, accg0, 0, 0, 0);
                accu0 = __builtin_amdgcn_mfma_f32_16x16x32_bf16(aA0, bu, accu0, 0, 0, 0);
                accg1 = __builtin_amdgcn_mfma_f32_16x16x32_bf16(aA1, bg, accg1, 0, 0, 0);
                accu1 = __builtin_amdgcn_mfma_f32_16x16x32_bf16(aA1, bu, accu1, 0, 0, 0);
            }
            const int k2 = (t + 2) * GK;
            if (k2 < HH) {   // issue slab k2 -> set A
                aA0 = *(const short8v*)(pA0 + k2);
                aA1 = *(const short8v*)(pA1 + k2);
                gA0 = *(const float4*)(pG + k2); gA1 = *(const float4*)(pG + k2 + 4);
                uA0 = *(const float4*)(pU + k2); uA1 = *(const float4*)(pU + k2 + 4);
            }
            // compute set B (slab k1)
            {
                short8v bg = pack8(gB0, gB1), bu = pack8(uB0, uB1);
                accg0 = __builtin_amdgcn_mfma_f32_16x16x32_bf16(aB0, bg, accg0, 0, 0, 0);
                accu0 = __builtin_amdgcn_mfma_f32_16x16x32_bf16(aB0, bu, accu0, 0, 0, 0);
                accg1 = __builtin_amdgcn_mfma_f32_16x16x32_bf16(aB1, bg, accg1, 0, 0, 0);
                accu1 = __builtin_amdgcn_mfma_f32_16x16x32_bf16(aB1, bu, accu1, 0, 0, 0);
            }
        }

        #pragma unroll
        for (int r = 0; r < 4; ++r) {
            int m0 = w * 32 + quad * 4 + r;
            int s0 = ssl[m0];
            if (s0 >= 0) {
                float g = accg0[r], u = accu0[r];
                hmid[(size_t)s0 * II + c_base + mcol] =
                    f2bf(swv[m0] * g * u / (1.f + __expf(-g)));
            }
            int m1 = w * 32 + 16 + quad * 4 + r;
            int s1 = ssl[m1];
            if (s1 >= 0) {
                float g = accg1[r], u = accu1[r];
                hmid[(size_t)s1 * II + c_base + mcol] =
                    f2bf(swv[m1] * g * u / (1.f + __expf(-g)));
            }
        }
    }
}

// ================= Phase C: down bf16 MFMA -> ydown ===========================
// grid 1024 = E(32) x 32 tiles of 32 out cols. 4 waves split M (32 rows each).
// 2-deep prefetch. NT = 16.
__global__ __launch_bounds__(256, 4) void kC(
    const short* __restrict__ hmid, const float* __restrict__ wd,
    const int* __restrict__ counts, const int* __restrict__ slots,
    short* __restrict__ ydown)
{
    __shared__ int ssl[GM];
    const int bx = blockIdx.x, tid = threadIdx.x;
    const int e      = bx >> 5;
    const int n_base = (bx & 31) * 32;
    const int cnt    = counts[e];
    const float* wb  = wd + (size_t)e * HH * II;

    const int lane = tid & 63;
    const int w    = tid >> 6;
    const int quad = lane >> 4;
    const int mcol = lane & 15;
    constexpr int NT = II / GK;       // 16 (even)

    const float* pW0 = wb + (size_t)(n_base +      mcol) * II + quad * 8;
    const float* pW1 = wb + (size_t)(n_base + 16 + mcol) * II + quad * 8;

    for (int m_base = 0; m_base < cnt; m_base += GM) {
        __syncthreads();
        if (tid < GM) {
            int m = m_base + tid;
            ssl[tid] = (m < cnt) ? slots[e * CAP + m] : -1;
        }
        __syncthreads();

        const short *pA0, *pA1;
        {
            int s0 = ssl[w * 32 +      mcol];
            int s1 = ssl[w * 32 + 16 + mcol];
            pA0 = hmid + (size_t)(s0 >= 0 ? s0 : 0) * II + quad * 8;
            pA1 = hmid + (size_t)(s1 >= 0 ? s1 : 0) * II + quad * 8;
        }

        floatx4 acc00 = {}, acc01 = {}, acc10 = {}, acc11 = {};
        short8v aA0, aA1, aB0, aB1;
        float4  p0A, p1A, q0A, q1A, p0B, p1B, q0B, q1B;

        aA0 = *(const short8v*)(pA0);
        aA1 = *(const short8v*)(pA1);
        p0A = *(const float4*)(pW0);     p1A = *(const float4*)(pW0 + 4);
        q0A = *(const float4*)(pW1);     q1A = *(const float4*)(pW1 + 4);

        for (int t = 0; t < NT; t += 2) {
            const int k1 = (t + 1) * GK;
            aB0 = *(const short8v*)(pA0 + k1);
            aB1 = *(const short8v*)(pA1 + k1);
            p0B = *(const float4*)(pW0 + k1); p1B = *(const float4*)(pW0 + k1 + 4);
            q0B = *(const float4*)(pW1 + k1); q1B = *(const float4*)(pW1 + k1 + 4);
            {
                short8v b0 = pack8(p0A, p1A), b1 = pack8(q0A, q1A);
                acc00 = __builtin_amdgcn_mfma_f32_16x16x32_bf16(aA0, b0, acc00, 0, 0, 0);
                acc01 = __builtin_amdgcn_mfma_f32_16x16x32_bf16(aA0, b1, acc01, 0, 0, 0);
                acc10 = __builtin_amdgcn_mfma_f32_16x16x32_bf16(aA1, b0, acc10, 0, 0, 0);
                acc11 = __builtin_amdgcn_mfma_f32_16x16x32_bf16(aA1, b1, acc11, 0, 0, 0);
            }
            const int k2 = (t + 2) * GK;
            if (k2 < II) {
                aA0 = *(const short8v*)(pA0 + k2);
                aA1 = *(const short8v*)(pA1 + k2);
                p0A = *(const float4*)(pW0 + k2); p1A = *(const float4*)(pW0 + k2 + 4);
                q0A = *(const float4*)(pW1 + k2); q1A = *(const float4*)(pW1 + k2 + 4);
            }
            {
                short8v b0 = pack8(p0B, p1B), b1 = pack8(q0B, q1B);
                acc00 = __builtin_amdgcn_mfma_f32_16x16x32_bf16(aB0, b0, acc00, 0, 0, 0);
                acc01 = __builtin_amdgcn_mfma_f32_16x16x32_bf16(aB0, b1, acc01, 0, 0, 0);
                acc10 = __builtin_amdgcn_mfma_f32_16x16x32_bf16(aB1, b0, acc10, 0, 0, 0);
                acc11 = __builtin_amdgcn_mfma_f32_16x16x32_bf16(aB1, b1, acc11, 0, 0, 0);
            }
        }

        #pragma unroll
        for (int r = 0; r < 4; ++r) {
            int m0 = w * 32 + quad * 4 + r;
            int s0 = ssl[m0];
            if (s0 >= 0) {
                short* yrow = ydown + (size_t)s0 * HH + n_base;
                yrow[mcol]      = f2bf(acc00[r]);
                yrow[16 + mcol] = f2bf(acc01[r]);
            }
            int m1 = w * 32 + 16 + quad * 4 + r;
            int s1 = ssl[m1];
            if (s1 >= 0) {
                short* yrow = ydown + (size_t)s1 * HH + n_base;
                yrow[mcol]      = f2bf(acc10[r]);
                yrow[16 + mcol] = f2bf(acc11[r]);
            }
        }
    }
}

// ================= Phase D: combine (grid 1024, 1 token/block) ================
__global__ __launch_bounds__(256, 4) void kD(
    const float* __restrict__ x, const short* __restrict__ ydown,
    const int* __restrict__ kexp, const float* __restrict__ zero_w,
    float* __restrict__ out)
{
    const int bx = blockIdx.x, tid = threadIdx.x;
    const int t = bx;
    const float4 xvv = ((const float4*)(x + (size_t)t * HH))[tid];
    const float zw = zero_w[t];
    float4 o;
    o.x = zw * xvv.x; o.y = zw * xvv.y; o.z = zw * xvv.z; o.w = zw * xvv.w;
    #pragma unroll
    for (int k = 0; k < TOPK; ++k) {
        int slot = t * TOPK + k;
        if (kexp[slot] < EE) {
            short4v y = *(const short4v*)&ydown[(size_t)slot * HH + tid * 4];
            o.x += bf2f(y[0]); o.y += bf2f(y[1]);
            o.z += bf2f(y[2]); o.w += bf2f(y[3]);
        }
    }
    ((float4*)(out + (size_t)t * HH))[tid] = o;
}

extern "C" void kernel_launch(void* const* d_in, const int* in_sizes, int n_in,
                              void* d_out, int out_size, void* d_ws, size_t ws_size,
                              hipStream_t stream) {
    const float* x    = (const float*)d_in[0];
    const float* rw   = (const float*)d_in[1];
    const float* bias = (const float*)d_in[2];
    const float* wgu  = (const float*)d_in[3];
    const float* wd   = (const float*)d_in[4];
    float* out = (float*)d_out;

    char* ws = (char*)d_ws;
    int*   counts = (int*)ws;
    float* topk_w = (float*)(ws + 1024);
    float* zero_w = (float*)(ws + 17408);
    int*   kexp   = (int*)(ws + 21504);
    int*   slots  = (int*)(ws + 40960);
    short* xb     = (short*)(ws + 262144);
    short* hmid   = (short*)(ws + 2359296);
    short* ydown  = (short*)(ws + 6553600);

    kA <<<dim3(512),  dim3(256), 0, stream>>>(x, rw, bias, topk_w, zero_w, kexp, xb);
    kA2<<<dim3(32),   dim3(256), 0, stream>>>(kexp, counts, slots);
    kB <<<dim3(1024), dim3(256), 0, stream>>>(xb, wgu, counts, slots, topk_w, hmid);
    kC <<<dim3(1024), dim3(256), 0, stream>>>(hmid, wd, counts, slots, ydown);
    kD <<<dim3(1024), dim3(256), 0, stream>>>(x, ydown, kexp, zero_w, out);
}

// Round 8
// 311.140 us; speedup vs baseline: 1.2560x; 1.1288x over previous
//
#include <hip/hip_runtime.h>
#include <hip/hip_bf16.h>
#include <math.h>

#define TT   1024
#define HH   1024
#define II   512
#define EE   32
#define NE   40
#define TOPK 4
#define CAP  1024

#define GM  128   // m-tile (slots) per block pass
#define GK  32    // k-slab (elements) per pipeline step

typedef __attribute__((ext_vector_type(4))) short short4v;
typedef __attribute__((ext_vector_type(8))) short short8v;
typedef __attribute__((ext_vector_type(4))) float floatx4;

#define FENCE() asm volatile("" ::: "memory")

static __device__ __forceinline__ short f2bf(float f) {
    unsigned u = __float_as_uint(f);
    unsigned r = (u + 0x7fffu + ((u >> 16) & 1u)) >> 16;
    return (short)(r & 0xffffu);
}
static __device__ __forceinline__ float bf2f(short s) {
    return __uint_as_float(((unsigned)(unsigned short)s) << 16);
}
#if defined(__has_builtin)
#if __has_builtin(__builtin_amdgcn_cvt_pk_bf16_f32)
#define HAVE_PK_BF16 1
#endif
#endif
static __device__ __forceinline__ unsigned pk2(float a, float b) {
#ifdef HAVE_PK_BF16
    typedef __attribute__((ext_vector_type(2))) __bf16 bf2t;
    union { bf2t v; unsigned u; } cv;
    cv.v = __builtin_amdgcn_cvt_pk_bf16_f32(a, b);
    return cv.u;
#else
    return (unsigned)(unsigned short)f2bf(a) | ((unsigned)(unsigned short)f2bf(b) << 16);
#endif
}
static __device__ __forceinline__ short4v cvt4(float4 v) {
    union { unsigned u[2]; short4v s; } cv;
    cv.u[0] = pk2(v.x, v.y); cv.u[1] = pk2(v.z, v.w);
    return cv.s;
}
static __device__ __forceinline__ short8v pack8(float4 f0, float4 f1) {
    union { short4v h[2]; short8v v; } u;
    u.h[0] = cvt4(f0); u.h[1] = cvt4(f1);
    return u.v;
}
// async global->LDS, 16B per lane; LDS dest = (wave-uniform base) + lane*16
static __device__ __forceinline__ void gload_lds16(const float* g, float* l) {
    __builtin_amdgcn_global_load_lds(
        (const __attribute__((address_space(1))) unsigned int*)g,
        (__attribute__((address_space(3))) unsigned int*)l, 16, 0, 0);
}

// ---------------- workspace layout (bytes) ----------------
// counts @0, topk_w @1024, zero_w @17408, kexp @21504, slots @40960,
// xb @262144 (2MB), hmid @2359296 (4MB), ydown @6553600 (8MB)

// ================= Phase A: router (waves 0,1) + xconv (waves 2,3) ============
__global__ __launch_bounds__(256, 4) void kA(
    const float* __restrict__ x, const float* __restrict__ rw,
    const float* __restrict__ bias, float* __restrict__ topk_w,
    float* __restrict__ zero_w, int* __restrict__ kexp,
    short* __restrict__ xb)
{
    const int bx = blockIdx.x, tid = threadIdx.x;
    const int lane = tid & 63;
    const int w    = tid >> 6;

    if (w < 2) {
        const int t = bx * 2 + w;
        float xv[16];
        #pragma unroll
        for (int i = 0; i < 16; ++i) xv[i] = x[(size_t)t * HH + 64 * i + lane];

        float mylogit = -INFINITY;
        for (int e0 = 0; e0 < NE; e0 += 4) {
            const float* r0 = rw + (size_t)e0 * HH;
            float p[4] = { 0.f, 0.f, 0.f, 0.f };
            #pragma unroll
            for (int i = 0; i < 16; ++i) {
                int h = 64 * i + lane;
                #pragma unroll
                for (int j = 0; j < 4; ++j) p[j] += xv[i] * r0[(size_t)j * HH + h];
            }
            #pragma unroll
            for (int j = 0; j < 4; ++j) {
                #pragma unroll
                for (int off = 32; off > 0; off >>= 1) p[j] += __shfl_xor(p[j], off);
                if (lane == e0 + j) mylogit = p[j];
            }
        }

        float m = mylogit;
        #pragma unroll
        for (int off = 32; off > 0; off >>= 1) m = fmaxf(m, __shfl_xor(m, off));
        float pexp = (lane < NE) ? expf(mylogit - m) : 0.f;
        float s = pexp;
        #pragma unroll
        for (int off = 32; off > 0; off >>= 1) s += __shfl_xor(s, off);
        const float score = pexp / s;

        float val = (lane < NE) ? score + bias[lane] : -INFINITY;
        int   kidx[TOPK];
        float kw[TOPK];
        #pragma unroll
        for (int k = 0; k < TOPK; ++k) {
            float v = val; int idx = lane;
            #pragma unroll
            for (int off = 32; off > 0; off >>= 1) {
                float ov = __shfl_xor(v, off);
                int   oi = __shfl_xor(idx, off);
                if (ov > v || (ov == v && oi < idx)) { v = ov; idx = oi; }
            }
            kidx[k] = idx;
            kw[k]   = __shfl(score, idx);
            if (lane == idx) val = -INFINITY;
        }

        if (lane == 0) {
            float zw = 0.f;
            #pragma unroll
            for (int k = 0; k < TOPK; ++k) {
                int slot = t * TOPK + k;
                topk_w[slot] = kw[k];
                kexp[slot]   = kidx[k];
                if (kidx[k] >= EE) zw += kw[k];
            }
            zero_w[t] = zw;
        }
    } else {
        const int t = bx * 2 + (w - 2);
        const float4* xr = (const float4*)(x + (size_t)t * HH);
        short4v* xbr = (short4v*)(xb + (size_t)t * HH);
        #pragma unroll
        for (int i = 0; i < 4; ++i) xbr[lane + 64 * i] = cvt4(xr[lane + 64 * i]);
    }
}

// ================= Phase A2: per-expert slot compaction (token-ordered) =======
__global__ __launch_bounds__(256, 4) void kA2(
    const int* __restrict__ kexp, int* __restrict__ counts,
    int* __restrict__ slots)
{
    __shared__ int wsum[4];
    __shared__ int base;
    const int e = blockIdx.x;
    const int tid = threadIdx.x, lane = tid & 63, w = tid >> 6;
    if (tid == 0) base = 0;
    __syncthreads();
    for (int i0 = 0; i0 < TT * TOPK; i0 += 256) {
        const int i = i0 + tid;
        const bool m = (kexp[i] == e);
        unsigned long long bal = __ballot(m);
        int pre  = __popcll(bal & ((1ull << lane) - 1ull));
        int wcnt = __popcll(bal);
        if (lane == 0) wsum[w] = wcnt;
        __syncthreads();
        int woff = 0;
        #pragma unroll
        for (int j = 0; j < 4; ++j) if (j < w) woff += wsum[j];
        const int tot = wsum[0] + wsum[1] + wsum[2] + wsum[3];
        if (m) slots[e * CAP + base + woff + pre] = i;
        __syncthreads();
        if (tid == 0) base += tot;
        __syncthreads();
    }
    if (tid == 0) counts[e] = base;
}

// ================= Phase B: gate_up bf16 MFMA + SiLU ==========================
// grid 1024 = E(32) x 32 tiles of 16 hmid cols; 4 waves split M (32 rows each).
// Weights DMA'd to LDS via global_load_lds (6 slabs in flight, counted vmcnt,
// one raw s_barrier per slab). Source-side XOR swizzle (part ^= row&7) keeps
// LDS dest linear while ds_reads are bank-conflict-free. A: 2-deep registers.
__global__ __launch_bounds__(256, 4) void kB(
    const short* __restrict__ xb, const float* __restrict__ wgu,
    const int* __restrict__ counts, const int* __restrict__ slots,
    const float* __restrict__ topk_w, short* __restrict__ hmid)
{
    __shared__ float smB[8][1024];   // 8 bufs x 4KB (32 rows x 128B)
    __shared__ int   ssl[GM];
    __shared__ float swv[GM];
    const int bx = blockIdx.x, tid = threadIdx.x;
    const int e      = bx >> 5;
    const int c_base = (bx & 31) * 16;
    const int cnt    = counts[e];
    const float* wb  = wgu + (size_t)e * (2 * II) * HH;

    const int lane = tid & 63;
    const int w    = tid >> 6;        // wave owns m-rows [w*32, w*32+32)
    const int quad = lane >> 4;
    const int mcol = lane & 15;
    constexpr int NT = HH / GK;       // 32

    // DMA source mapping: thread -> (row, swizzled part)
    const int srow  = tid >> 3;                    // 0..31
    const int spart = (tid & 7) ^ (srow & 7);      // source-side XOR swizzle
    const int grow  = (srow < 16) ? (c_base + srow) : (II + c_base + (srow - 16));
    const float* srcB = wb + (size_t)grow * HH + spart * 4;

    // swizzled read offsets (bytes within one 4KB buf)
    const int swz  = (mcol & 7) << 4;
    const int offG = ((mcol * 128 + quad * 32) ^ swz);
    const int offU = (((16 + mcol) * 128 + quad * 32) ^ swz);

#define STAGE_B(s) gload_lds16(srcB + (size_t)(s) * GK, &smB[(s) & 7][0] + w * 256)

#define BODY_B(s, A0, A1, NSTR) do { \
    asm volatile("s_waitcnt vmcnt(" NSTR ")" ::: "memory"); \
    __builtin_amdgcn_s_barrier(); \
    FENCE(); \
    const char* bb = (const char*)&smB[(s) & 7][0]; \
    float4 g0 = *(const float4*)(bb + offG); \
    float4 g1 = *(const float4*)(bb + (offG ^ 16)); \
    float4 u0 = *(const float4*)(bb + offU); \
    float4 u1 = *(const float4*)(bb + (offU ^ 16)); \
    short8v bg = pack8(g0, g1), bu = pack8(u0, u1); \
    accg0 = __builtin_amdgcn_mfma_f32_16x16x32_bf16(A0, bg, accg0, 0, 0, 0); \
    accu0 = __builtin_amdgcn_mfma_f32_16x16x32_bf16(A0, bu, accu0, 0, 0, 0); \
    accg1 = __builtin_amdgcn_mfma_f32_16x16x32_bf16(A1, bg, accg1, 0, 0, 0); \
    accu1 = __builtin_amdgcn_mfma_f32_16x16x32_bf16(A1, bu, accu1, 0, 0, 0); \
} while (0)

    for (int m_base = 0; m_base < cnt; m_base += GM) {
        __syncthreads();
        if (tid < GM) {
            int m = m_base + tid;
            int s = (m < cnt) ? slots[e * CAP + m] : -1;
            ssl[tid] = s;
            swv[tid] = (s >= 0) ? topk_w[s] : 0.f;
        }
        __syncthreads();

        const short *pA0, *pA1;
        {
            int s0 = ssl[w * 32 +      mcol];
            int s1 = ssl[w * 32 + 16 + mcol];
            pA0 = xb + (size_t)((s0 >= 0 ? s0 : 0) >> 2) * HH + quad * 8;
            pA1 = xb + (size_t)((s1 >= 0 ? s1 : 0) >> 2) * HH + quad * 8;
        }

        floatx4 accg0 = {}, accg1 = {}, accu0 = {}, accu1 = {};
        short8v aA0, aA1, aB0, aB1;

        // prologue: DMA slabs 0..5 (fenced per issue -> deterministic order),
        // then A slabs 0,1 into register sets.
        STAGE_B(0); FENCE(); STAGE_B(1); FENCE(); STAGE_B(2); FENCE();
        STAGE_B(3); FENCE(); STAGE_B(4); FENCE(); STAGE_B(5); FENCE();
        aA0 = *(const short8v*)(pA0);
        aA1 = *(const short8v*)(pA1);
        aB0 = *(const short8v*)(pA0 + GK);
        aB1 = *(const short8v*)(pA1 + GK);
        FENCE();

        // main: slabs 0..NT-7; window per slab = {2 A loads, 1 DMA} -> vmcnt(9)
        for (int s = 0; s < NT - 6; s += 2) {
            BODY_B(s, aA0, aA1, "9");
            aA0 = *(const short8v*)(pA0 + (s + 2) * GK);
            aA1 = *(const short8v*)(pA1 + (s + 2) * GK);
            STAGE_B(s + 6);
            BODY_B(s + 1, aB0, aB1, "9");
            aB0 = *(const short8v*)(pA0 + (s + 3) * GK);
            aB1 = *(const short8v*)(pA1 + (s + 3) * GK);
            STAGE_B(s + 7);
        }
        // tail: slabs NT-6..NT-1, fully drained waits
        for (int s = NT - 6; s < NT; s += 2) {
            BODY_B(s, aA0, aA1, "0");
            if (s + 2 < NT) {
                aA0 = *(const short8v*)(pA0 + (s + 2) * GK);
                aA1 = *(const short8v*)(pA1 + (s + 2) * GK);
            }
            BODY_B(s + 1, aB0, aB1, "0");
            if (s + 3 < NT) {
                aB0 = *(const short8v*)(pA0 + (s + 3) * GK);
                aB1 = *(const short8v*)(pA1 + (s + 3) * GK);
            }
        }

        #pragma unroll
        for (int r = 0; r < 4; ++r) {
            int m0 = w * 32 + quad * 4 + r;
            int s0 = ssl[m0];
            if (s0 >= 0) {
                float g = accg0[r], u = accu0[r];
                hmid[(size_t)s0 * II + c_base + mcol] =
                    f2bf(swv[m0] * g * u / (1.f + __expf(-g)));
            }
            int m1 = w * 32 + 16 + quad * 4 + r;
            int s1 = ssl[m1];
            if (s1 >= 0) {
                float g = accg1[r], u = accu1[r];
                hmid[(size_t)s1 * II + c_base + mcol] =
                    f2bf(swv[m1] * g * u / (1.f + __expf(-g)));
            }
        }
    }
#undef STAGE_B
#undef BODY_B
}

// ================= Phase C: down bf16 MFMA -> ydown ===========================
// grid 1024 = E(32) x 32 tiles of 32 out cols; same DMA-staged weight pipeline.
__global__ __launch_bounds__(256, 4) void kC(
    const short* __restrict__ hmid, const float* __restrict__ wd,
    const int* __restrict__ counts, const int* __restrict__ slots,
    short* __restrict__ ydown)
{
    __shared__ float smC[8][1024];
    __shared__ int   ssl[GM];
    const int bx = blockIdx.x, tid = threadIdx.x;
    const int e      = bx >> 5;
    const int n_base = (bx & 31) * 32;
    const int cnt    = counts[e];
    const float* wb  = wd + (size_t)e * HH * II;

    const int lane = tid & 63;
    const int w    = tid >> 6;
    const int quad = lane >> 4;
    const int mcol = lane & 15;
    constexpr int NT = II / GK;       // 16

    const int srow  = tid >> 3;                    // 0..31 (= out col - n_base)
    const int spart = (tid & 7) ^ (srow & 7);
    const float* srcB = wb + (size_t)(n_base + srow) * II + spart * 4;

    const int swz  = (mcol & 7) << 4;
    const int off0 = ((mcol * 128 + quad * 32) ^ swz);
    const int off1 = (((16 + mcol) * 128 + quad * 32) ^ swz);

#define STAGE_C(s) gload_lds16(srcB + (size_t)(s) * GK, &smC[(s) & 7][0] + w * 256)

#define BODY_C(s, A0, A1, NSTR) do { \
    asm volatile("s_waitcnt vmcnt(" NSTR ")" ::: "memory"); \
    __builtin_amdgcn_s_barrier(); \
    FENCE(); \
    const char* bb = (const char*)&smC[(s) & 7][0]; \
    float4 p0 = *(const float4*)(bb + off0); \
    float4 p1 = *(const float4*)(bb + (off0 ^ 16)); \
    float4 q0 = *(const float4*)(bb + off1); \
    float4 q1 = *(const float4*)(bb + (off1 ^ 16)); \
    short8v b0 = pack8(p0, p1), b1 = pack8(q0, q1); \
    acc00 = __builtin_amdgcn_mfma_f32_16x16x32_bf16(A0, b0, acc00, 0, 0, 0); \
    acc01 = __builtin_amdgcn_mfma_f32_16x16x32_bf16(A0, b1, acc01, 0, 0, 0); \
    acc10 = __builtin_amdgcn_mfma_f32_16x16x32_bf16(A1, b0, acc10, 0, 0, 0); \
    acc11 = __builtin_amdgcn_mfma_f32_16x16x32_bf16(A1, b1, acc11, 0, 0, 0); \
} while (0)

    for (int m_base = 0; m_base < cnt; m_base += GM) {
        __syncthreads();
        if (tid < GM) {
            int m = m_base + tid;
            ssl[tid] = (m < cnt) ? slots[e * CAP + m] : -1;
        }
        __syncthreads();

        const short *pA0, *pA1;
        {
            int s0 = ssl[w * 32 +      mcol];
            int s1 = ssl[w * 32 + 16 + mcol];
            pA0 = hmid + (size_t)(s0 >= 0 ? s0 : 0) * II + quad * 8;
            pA1 = hmid + (size_t)(s1 >= 0 ? s1 : 0) * II + quad * 8;
        }

        floatx4 acc00 = {}, acc01 = {}, acc10 = {}, acc11 = {};
        short8v aA0, aA1, aB0, aB1;

        STAGE_C(0); FENCE(); STAGE_C(1); FENCE(); STAGE_C(2); FENCE();
        STAGE_C(3); FENCE(); STAGE_C(4); FENCE(); STAGE_C(5); FENCE();
        aA0 = *(const short8v*)(pA0);
        aA1 = *(const short8v*)(pA1);
        aB0 = *(const short8v*)(pA0 + GK);
        aB1 = *(const short8v*)(pA1 + GK);
        FENCE();

        for (int s = 0; s < NT - 6; s += 2) {
            BODY_C(s, aA0, aA1, "9");
            aA0 = *(const short8v*)(pA0 + (s + 2) * GK);
            aA1 = *(const short8v*)(pA1 + (s + 2) * GK);
            STAGE_C(s + 6);
            BODY_C(s + 1, aB0, aB1, "9");
            aB0 = *(const short8v*)(pA0 + (s + 3) * GK);
            aB1 = *(const short8v*)(pA1 + (s + 3) * GK);
            STAGE_C(s + 7);
        }
        for (int s = NT - 6; s < NT; s += 2) {
            BODY_C(s, aA0, aA1, "0");
            if (s + 2 < NT) {
                aA0 = *(const short8v*)(pA0 + (s + 2) * GK);
                aA1 = *(const short8v*)(pA1 + (s + 2) * GK);
            }
            BODY_C(s + 1, aB0, aB1, "0");
            if (s + 3 < NT) {
                aB0 = *(const short8v*)(pA0 + (s + 3) * GK);
                aB1 = *(const short8v*)(pA1 + (s + 3) * GK);
            }
        }

        #pragma unroll
        for (int r = 0; r < 4; ++r) {
            int m0 = w * 32 + quad * 4 + r;
            int s0 = ssl[m0];
            if (s0 >= 0) {
                short* yrow = ydown + (size_t)s0 * HH + n_base;
                yrow[mcol]      = f2bf(acc00[r]);
                yrow[16 + mcol] = f2bf(acc01[r]);
            }
            int m1 = w * 32 + 16 + quad * 4 + r;
            int s1 = ssl[m1];
            if (s1 >= 0) {
                short* yrow = ydown + (size_t)s1 * HH + n_base;
                yrow[mcol]      = f2bf(acc10[r]);
                yrow[16 + mcol] = f2bf(acc11[r]);
            }
        }
    }
#undef STAGE_C
#undef BODY_C
}

// ================= Phase D: combine (grid 1024, 1 token/block) ================
__global__ __launch_bounds__(256, 4) void kD(
    const float* __restrict__ x, const short* __restrict__ ydown,
    const int* __restrict__ kexp, const float* __restrict__ zero_w,
    float* __restrict__ out)
{
    const int bx = blockIdx.x, tid = threadIdx.x;
    const int t = bx;
    const float4 xvv = ((const float4*)(x + (size_t)t * HH))[tid];
    const float zw = zero_w[t];
    float4 o;
    o.x = zw * xvv.x; o.y = zw * xvv.y; o.z = zw * xvv.z; o.w = zw * xvv.w;
    #pragma unroll
    for (int k = 0; k < TOPK; ++k) {
        int slot = t * TOPK + k;
        if (kexp[slot] < EE) {
            short4v y = *(const short4v*)&ydown[(size_t)slot * HH + tid * 4];
            o.x += bf2f(y[0]); o.y += bf2f(y[1]);
            o.z += bf2f(y[2]); o.w += bf2f(y[3]);
        }
    }
    ((float4*)(out + (size_t)t * HH))[tid] = o;
}

extern "C" void kernel_launch(void* const* d_in, const int* in_sizes, int n_in,
                              void* d_out, int out_size, void* d_ws, size_t ws_size,
                              hipStream_t stream) {
    const float* x    = (const float*)d_in[0];
    const float* rw   = (const float*)d_in[1];
    const float* bias = (const float*)d_in[2];
    const float* wgu  = (const float*)d_in[3];
    const float* wd   = (const float*)d_in[4];
    float* out = (float*)d_out;

    char* ws = (char*)d_ws;
    int*   counts = (int*)ws;
    float* topk_w = (float*)(ws + 1024);
    float* zero_w = (float*)(ws + 17408);
    int*   kexp   = (int*)(ws + 21504);
    int*   slots  = (int*)(ws + 40960);
    short* xb     = (short*)(ws + 262144);
    short* hmid   = (short*)(ws + 2359296);
    short* ydown  = (short*)(ws + 6553600);

    kA <<<dim3(512),  dim3(256), 0, stream>>>(x, rw, bias, topk_w, zero_w, kexp, xb);
    kA2<<<dim3(32),   dim3(256), 0, stream>>>(kexp, counts, slots);
    kB <<<dim3(1024), dim3(256), 0, stream>>>(xb, wgu, counts, slots, topk_w, hmid);
    kC <<<dim3(1024), dim3(256), 0, stream>>>(hmid, wd, counts, slots, ydown);
    kD <<<dim3(1024), dim3(256), 0, stream>>>(x, ydown, kexp, zero_w, out);
}